// Round 7
// baseline (15061.603 us; speedup 1.0000x reference)
//
#include <hip/hip_runtime.h>
#include <stddef.h>

typedef unsigned int u32;

#define TT 512
#define TC 64        // timestep chunk
#define NCHUNK 8
#define XHS 10368    // xh row stride (floats); 2*XHS*4 + gl pads LDS to force 1 block/CU

__device__ __forceinline__ float sigmoidf_(float x) {
    return 1.0f / (1.0f + __expf(-x));
}
__device__ __forceinline__ float tanhf_(float x) {
    float ax = fabsf(x);
    float e = __expf(-2.0f * ax);
    float t = (1.0f - e) / (1.0f + e);
    return copysignf(t, x);
}

// ---- per-access coherent (IF$-level) ops: no cache-wide inv/wb, no RMW ----
__device__ __forceinline__ float4 ldg_cv4(const float* p) {
    float4 v;
    asm volatile("global_load_dwordx4 %0, %1, off sc0 sc1\n\t"
                 "s_waitcnt vmcnt(0)"
                 : "=v"(v) : "v"(p) : "memory");
    return v;
}
__device__ __forceinline__ u32 ldg_cu32(const u32* p) {
    u32 v;
    asm volatile("global_load_dword %0, %1, off sc0 sc1\n\t"
                 "s_waitcnt vmcnt(0)"
                 : "=v"(v) : "v"(p) : "memory");
    return v;
}
__device__ __forceinline__ void stg_cv1(float* p, float v) {
    asm volatile("global_store_dword %0, %1, off sc0 sc1"
                 :: "v"(p), "v"(v) : "memory");
}
__device__ __forceinline__ void stg_cu32(u32* p, u32 v) {
    asm volatile("global_store_dword %0, %1, off sc0 sc1"
                 :: "v"(p), "v"(v) : "memory");
}

// ============================================================================
// proj_gemm: xW[tl][j][b] = sum_k W[j][k] * X[b*sXb + (t0+t)*sXt + k] + bih[j] + bhh[j]
//   M=2048, N = 64t x 32b, K=512; tile 128x128, 256 threads, 8x8 register tile.
// ============================================================================
#define APITCH 132
#define BPITCH 132

__global__ void __launch_bounds__(256, 2)
proj_gemm(const float* __restrict__ W,
          const float* __restrict__ bih, const float* __restrict__ bhh,
          const float* __restrict__ X, size_t sXb, size_t sXt, int t0,
          float* __restrict__ xW)
{
    __shared__ float As[32][APITCH];   // [k][m]
    __shared__ float Bs[32][BPITCH];   // [k][n]
    const int tid = threadIdx.x;
    const int mbase = blockIdx.x * 128;
    const int nt = blockIdx.y;
    const int tm = tid >> 4;
    const int tn = tid & 15;
    float acc[8][8] = {};

    for (int kc = 0; kc < 512; kc += 32) {
        __syncthreads();
#pragma unroll
        for (int u = 0; u < 4; ++u) {
            const int f = u * 256 + tid;
            const int m = f >> 3, k4 = f & 7;
            const float4 v = *(const float4*)(W + (size_t)(mbase + m) * 512 + kc + k4 * 4);
            As[k4 * 4 + 0][m] = v.x; As[k4 * 4 + 1][m] = v.y;
            As[k4 * 4 + 2][m] = v.z; As[k4 * 4 + 3][m] = v.w;
        }
#pragma unroll
        for (int u = 0; u < 4; ++u) {
            const int f = u * 256 + tid;
            const int n = f >> 3, k4 = f & 7;
            const int tl = n >> 5, b = n & 31;
            const float4 v = *(const float4*)(X + (size_t)b * sXb +
                                              (size_t)(t0 + nt * 4 + tl) * sXt + kc + k4 * 4);
            Bs[k4 * 4 + 0][n] = v.x; Bs[k4 * 4 + 1][n] = v.y;
            Bs[k4 * 4 + 2][n] = v.z; Bs[k4 * 4 + 3][n] = v.w;
        }
        __syncthreads();
#pragma unroll 8
        for (int kk = 0; kk < 32; ++kk) {
            const float4 a0 = *(const float4*)&As[kk][tm * 8];
            const float4 a1 = *(const float4*)&As[kk][tm * 8 + 4];
            const float4 b0 = *(const float4*)&Bs[kk][tn * 8];
            const float4 b1 = *(const float4*)&Bs[kk][tn * 8 + 4];
            const float am[8] = {a0.x,a0.y,a0.z,a0.w,a1.x,a1.y,a1.z,a1.w};
            const float bn[8] = {b0.x,b0.y,b0.z,b0.w,b1.x,b1.y,b1.z,b1.w};
#pragma unroll
            for (int i = 0; i < 8; ++i)
#pragma unroll
                for (int j = 0; j < 8; ++j)
                    acc[i][j] = fmaf(am[i], bn[j], acc[i][j]);
        }
    }
    const int tl_loc = nt * 4 + (tn >> 2);
    const int bcol = (tn & 3) * 8;
#pragma unroll
    for (int i = 0; i < 8; ++i) {
        const int m = mbase + tm * 8 + i;
        const float bias = bih[m] + bhh[m];
        float* dst = xW + ((size_t)tl_loc * 2048 + m) * 32 + bcol;
        float4 v0 = {acc[i][0] + bias, acc[i][1] + bias, acc[i][2] + bias, acc[i][3] + bias};
        float4 v1 = {acc[i][4] + bias, acc[i][5] + bias, acc[i][6] + bias, acc[i][7] + bias};
        *(float4*)dst = v0;
        *(float4*)(dst + 4) = v1;
    }
}

// ============================================================================
// lstm_rec: 256 blocks x 512 threads, 1 block/CU (LDS-forced), all resident.
//   chain = bid & 15 (2 batches, all 16 blocks on one XCD), rbi = bid >> 4
//   (32 hidden -> 128 gate rows). Thread (rgrp=tid>>4, ks=tid&15):
//   rows rgrp*4..+3, k-slice [ks*32, ks*32+32), w[4][32] in VGPRs.
//   Sync: per-block monotonic progress word, plain sc0sc1 store after vmcnt(0);
//   consumers poll 16 slots with parallel per-lane sc0sc1 loads. No atomics.
// ============================================================================
__global__ void __launch_bounds__(512, 1)
lstm_rec(const float* __restrict__ Whh,      // [2048][512]
         const float* __restrict__ xW,       // [TC][2048][32]
         float* __restrict__ hbuf,           // h at hbuf + t*sT + b*sB + hh
         size_t sT, size_t sB,
         float* __restrict__ cst,            // [32][512] c-state for this layer
         u32* __restrict__ prog,             // [16][16] progress for this layer
         int t0)
{
    __shared__ float xhf[2 * XHS];           // swizzled h(t-1), padded (82,944B total)
    __shared__ float glf[32 * 8];            // [hl][b][gate]

    const int tid = threadIdx.x;
    const int chain = blockIdx.x & 15;       // one XCD per chain (bid%8 = chain%8)
    const int rbi = blockIdx.x >> 4;
    const int hb = rbi * 32;                 // hidden slice [hb, hb+32)
    const int bb = chain * 2;                // batch slice [bb, bb+2)

    const int rgrp = tid >> 4;               // 0..31
    const int ks = tid & 15;                 // 0..15
    const int ks7 = ks & 7;

    // ---- load W_hh slice into registers (once): 4 rows x 32 k = 128 VGPRs ----
    float w[4][32];
#pragma unroll
    for (int i = 0; i < 4; ++i) {
        const int r = rgrp * 4 + i;
        const int j = ((r >> 5) << 9) + hb + (r & 31);
#pragma unroll
        for (int q8 = 0; q8 < 8; ++q8) {
            const float4 v = *(const float4*)(Whh + (size_t)j * 512 + ks * 32 + q8 * 4);
            w[i][q8 * 4 + 0] = v.x; w[i][q8 * 4 + 1] = v.y;
            w[i][q8 * 4 + 2] = v.z; w[i][q8 * 4 + 3] = v.w;
        }
    }
    // xwv-lane decode (ks<8): contributes xW for (i = ks>>1, b = ks&1)
    const int i_x = ks >> 1, b_x = ks & 1;
    const int r_x = rgrp * 4 + i_x;
    const int j_x = ((r_x >> 5) << 9) + hb + (r_x & 31);
    // update decode (tid<64)
    const int b_u = tid >> 5, hl_u = tid & 31;
    float c_reg = 0.0f;
    if (tid < 64) c_reg = cst[(size_t)(bb + b_u) * 512 + hb + hl_u];

    u32* slots = prog + chain * 16;
    __syncthreads();

    for (int t = t0; t < t0 + TC; ++t) {
        // prefetch precomputed input-projection (plain cached load, no dependency)
        float xwv = 0.0f;
        if (ks < 8)
            xwv = xW[((size_t)(t - t0) * 2048 + j_x) * 32 + bb + b_x];

        if (t > 0) {
            // wait for all 16 row-blocks of this chain to publish h(t-1)
            if (tid < 64) {
                bool ok;
                do {
                    u32 v = 0xFFFFFFFFu;
                    if (tid < 16) v = ldg_cu32(slots + tid);
                    ok = (v >= (u32)t);
                } while (!__all(ok));
            }
            __syncthreads();
            // stage h(t-1): 256 threads x one coherent float4, XOR quad-swizzle
            if (tid < 256) {
                const int b_s = tid >> 7, q = tid & 127;
                const float4 hv = ldg_cv4(hbuf + (size_t)(t - 1) * sT +
                                          (size_t)(bb + b_s) * sB + (size_t)q * 4);
                const int swq = q ^ ((q >> 3) & 7);
                *(float4*)&xhf[b_s * XHS + swq * 4] = hv;
            }
        }
        __syncthreads();

        float acc[4][2] = {};
        if (t > 0) {
#pragma unroll
            for (int jj = 0; jj < 8; ++jj) {
                const int sq = (ks * 8 + (jj ^ ks7)) * 4;   // swizzled quad offset
                const float4 x0 = *(const float4*)&xhf[sq];
                const float4 x1 = *(const float4*)&xhf[XHS + sq];
#pragma unroll
                for (int i = 0; i < 4; ++i) {
                    acc[i][0] = fmaf(w[i][jj*4+0], x0.x, acc[i][0]);
                    acc[i][0] = fmaf(w[i][jj*4+1], x0.y, acc[i][0]);
                    acc[i][0] = fmaf(w[i][jj*4+2], x0.z, acc[i][0]);
                    acc[i][0] = fmaf(w[i][jj*4+3], x0.w, acc[i][0]);
                    acc[i][1] = fmaf(w[i][jj*4+0], x1.x, acc[i][1]);
                    acc[i][1] = fmaf(w[i][jj*4+1], x1.y, acc[i][1]);
                    acc[i][1] = fmaf(w[i][jj*4+2], x1.z, acc[i][1]);
                    acc[i][1] = fmaf(w[i][jj*4+3], x1.w, acc[i][1]);
                }
            }
        }
        // fold xW in (each of the 8 values added by exactly one lane pre-reduce)
        if (ks < 8) acc[i_x][b_x] += xwv;
        // butterfly reduce over the 16 k-slice lanes (4 stages x 8 accs)
#pragma unroll
        for (int m = 1; m < 16; m <<= 1) {
#pragma unroll
            for (int i = 0; i < 4; ++i) {
                acc[i][0] += __shfl_xor(acc[i][0], m);
                acc[i][1] += __shfl_xor(acc[i][1], m);
            }
        }
        if (ks == 0) {
#pragma unroll
            for (int i = 0; i < 4; ++i) {
                const int r = rgrp * 4 + i;
                glf[((r & 31) << 3) + 0 + (r >> 5)] = acc[i][0];
                glf[((r & 31) << 3) + 4 + (r >> 5)] = acc[i][1];
            }
        }
        __syncthreads();
        if (tid < 64) {  // one thread per (batch, hidden) pair
            const float4 gv = *(const float4*)&glf[(hl_u << 3) + (b_u << 2)];
            const float i_ = sigmoidf_(gv.x);
            const float f_ = sigmoidf_(gv.y);
            const float g_ = tanhf_(gv.z);
            const float o_ = sigmoidf_(gv.w);
            c_reg = f_ * c_reg + i_ * g_;
            const float hv = o_ * tanhf_(c_reg);
            stg_cv1(hbuf + (size_t)t * sT + (size_t)(bb + b_u) * sB + hb + hl_u, hv);
            asm volatile("s_waitcnt vmcnt(0)" ::: "memory");   // h at coherent point
            if (tid == 0) stg_cu32(slots + rbi, (u32)(t + 1));
        }
        __syncthreads();
    }
    if (tid < 64) cst[(size_t)(bb + b_u) * 512 + hb + hl_u] = c_reg;
}

// ============================================================================
extern "C" void kernel_launch(void* const* d_in, const int* in_sizes, int n_in,
                              void* d_out, int out_size, void* d_ws, size_t ws_size,
                              hipStream_t stream) {
    const float* inp  = (const float*)d_in[0];
    const float* Wih0 = (const float*)d_in[1];
    const float* Whh0 = (const float*)d_in[2];
    const float* bih0 = (const float*)d_in[3];
    const float* bhh0 = (const float*)d_in[4];
    const float* Wih1 = (const float*)d_in[5];
    const float* Whh1 = (const float*)d_in[6];
    const float* bih1 = (const float*)d_in[7];
    const float* bhh1 = (const float*)d_in[8];
    float* out = (float*)d_out;

    char* ws = (char*)d_ws;
    float* h0seq = (float*)ws;                              // [512][32][512]  32 MB
    float* xW    = (float*)(ws + 33554432);                 // [64][2048][32]  16 MB
    float* cst   = (float*)(ws + 50331648);                 // [2][32][512]   128 KB
    u32*   prog  = (u32*)  (ws + 50331648 + 131072);        // [2][256]         2 KB
    (void)hipMemsetAsync(ws + 50331648, 0, 131072 + 2048, stream);

    const dim3 gg(16, 16), gb(256);
    const dim3 rg(256), rb(512);

    // layer 0: x-projection GEMM + recurrence, chunked over T
    for (int c = 0; c < NCHUNK; ++c) {
        const int t0 = c * TC;
        hipLaunchKernelGGL(proj_gemm, gg, gb, 0, stream,
                           Wih0, bih0, bhh0, inp, (size_t)512 * 512, (size_t)512, t0, xW);
        hipLaunchKernelGGL(lstm_rec, rg, rb, 0, stream,
                           Whh0, xW, h0seq, (size_t)32 * 512, (size_t)512,
                           cst, prog, t0);
    }
    // layer 1: input = h0seq; h published directly into d_out ([B][T][H])
    for (int c = 0; c < NCHUNK; ++c) {
        const int t0 = c * TC;
        hipLaunchKernelGGL(proj_gemm, gg, gb, 0, stream,
                           Wih1, bih1, bhh1, h0seq, (size_t)512, (size_t)32 * 512, t0, xW);
        hipLaunchKernelGGL(lstm_rec, rg, rb, 0, stream,
                           Whh1, xW, out, (size_t)512, (size_t)512 * 512,
                           cst + 32 * 512, prog + 256, t0);
    }
}

// Round 8
// 5865.357 us; speedup vs baseline: 2.5679x; 2.5679x over previous
//
#include <hip/hip_runtime.h>
#include <stddef.h>

typedef unsigned int u32;

#define TT 512
#define TC 64        // timestep chunk
#define NCHUNK 8

__device__ __forceinline__ float sigmoidf_(float x) {
    return 1.0f / (1.0f + __expf(-x));
}
__device__ __forceinline__ float tanhf_(float x) {
    float ax = fabsf(x);
    float e = __expf(-2.0f * ax);
    float t = (1.0f - e) / (1.0f + e);
    return copysignf(t, x);
}

// ---- per-access coherent (IF$-level) ops: no cache-wide inv/wb, no RMW ----
__device__ __forceinline__ float4 ldg_cv4(const float* p) {
    float4 v;
    asm volatile("global_load_dwordx4 %0, %1, off sc0 sc1\n\t"
                 "s_waitcnt vmcnt(0)"
                 : "=v"(v) : "v"(p) : "memory");
    return v;
}
__device__ __forceinline__ void stg_cv2(float* p, float2 v) {
    asm volatile("global_store_dwordx2 %0, %1, off sc0 sc1"
                 :: "v"(p), "v"(v) : "memory");
}

// ============================================================================
// proj_gemm: xW[tl][j][b] = sum_k W[j][k] * X[b*sXb + (t0+t)*sXt + k] + bih[j] + bhh[j]
//   M=2048, N = 64t x 32b, K=512; tile 128x128, 256 threads, 8x8 register tile.
// ============================================================================
#define APITCH 132
#define BPITCH 132

__global__ void __launch_bounds__(256, 2)
proj_gemm(const float* __restrict__ W,
          const float* __restrict__ bih, const float* __restrict__ bhh,
          const float* __restrict__ X, size_t sXb, size_t sXt, int t0,
          float* __restrict__ xW)
{
    __shared__ float As[32][APITCH];   // [k][m]
    __shared__ float Bs[32][BPITCH];   // [k][n]
    const int tid = threadIdx.x;
    const int mbase = blockIdx.x * 128;
    const int nt = blockIdx.y;
    const int tm = tid >> 4;
    const int tn = tid & 15;
    float acc[8][8] = {};

    for (int kc = 0; kc < 512; kc += 32) {
        __syncthreads();
#pragma unroll
        for (int u = 0; u < 4; ++u) {
            const int f = u * 256 + tid;
            const int m = f >> 3, k4 = f & 7;
            const float4 v = *(const float4*)(W + (size_t)(mbase + m) * 512 + kc + k4 * 4);
            As[k4 * 4 + 0][m] = v.x; As[k4 * 4 + 1][m] = v.y;
            As[k4 * 4 + 2][m] = v.z; As[k4 * 4 + 3][m] = v.w;
        }
#pragma unroll
        for (int u = 0; u < 4; ++u) {
            const int f = u * 256 + tid;
            const int n = f >> 3, k4 = f & 7;
            const int tl = n >> 5, b = n & 31;
            const float4 v = *(const float4*)(X + (size_t)b * sXb +
                                              (size_t)(t0 + nt * 4 + tl) * sXt + kc + k4 * 4);
            Bs[k4 * 4 + 0][n] = v.x; Bs[k4 * 4 + 1][n] = v.y;
            Bs[k4 * 4 + 2][n] = v.z; Bs[k4 * 4 + 3][n] = v.w;
        }
        __syncthreads();
#pragma unroll 8
        for (int kk = 0; kk < 32; ++kk) {
            const float4 a0 = *(const float4*)&As[kk][tm * 8];
            const float4 a1 = *(const float4*)&As[kk][tm * 8 + 4];
            const float4 b0 = *(const float4*)&Bs[kk][tn * 8];
            const float4 b1 = *(const float4*)&Bs[kk][tn * 8 + 4];
            const float am[8] = {a0.x,a0.y,a0.z,a0.w,a1.x,a1.y,a1.z,a1.w};
            const float bn[8] = {b0.x,b0.y,b0.z,b0.w,b1.x,b1.y,b1.z,b1.w};
#pragma unroll
            for (int i = 0; i < 8; ++i)
#pragma unroll
                for (int j = 0; j < 8; ++j)
                    acc[i][j] = fmaf(am[i], bn[j], acc[i][j]);
        }
    }
    const int tl_loc = nt * 4 + (tn >> 2);
    const int bcol = (tn & 3) * 8;
#pragma unroll
    for (int i = 0; i < 8; ++i) {
        const int m = mbase + tm * 8 + i;
        const float bias = bih[m] + bhh[m];
        float* dst = xW + ((size_t)tl_loc * 2048 + m) * 32 + bcol;
        float4 v0 = {acc[i][0] + bias, acc[i][1] + bias, acc[i][2] + bias, acc[i][3] + bias};
        float4 v1 = {acc[i][4] + bias, acc[i][5] + bias, acc[i][6] + bias, acc[i][7] + bias};
        *(float4*)dst = v0;
        *(float4*)(dst + 4) = v1;
    }
}

// ============================================================================
// lstm_rec: 256 blocks x 512 threads, all resident (grid == #CU; <=2 blocks/CU fit).
//   chain = bid & 7 (4 batches), rbi = bid >> 3 (16 hidden -> 64 gate rows).
//   Thread (rgrp=tid>>4 -> 2 rows, ks=tid&15 -> 32-wide k-slice): w[2][32] = 64 VGPRs.
//   Sync: tagged-data ring. Producer stores (h, tag=t+1) as one 8B sc0sc1 dwordx2;
//   consumers poll the staging loads' tag fields directly. No flags, no atomics,
//   one coherent round trip per step. Ring depth 4 (chain skew provably < 2).
// ============================================================================
__global__ void __launch_bounds__(512, 1)
lstm_rec(const float* __restrict__ Whh,      // [2048][512]
         const float* __restrict__ xW,       // [TC][2048][32]
         float* __restrict__ hbuf,           // plain h at hbuf + t*sT + b*sB + hh
         size_t sT, size_t sB,
         float* __restrict__ cst,            // [32][512] c-state for this layer
         float* __restrict__ ring,           // [4][32][512] float2 (h, tag)
         int t0)
{
    __shared__ float xh[4][512];             // quad-swizzled h(t-1)   8 KB
    __shared__ float gl[16][4][4];           // [hl][b][gate]          1 KB

    const int tid = threadIdx.x;
    const int chain = blockIdx.x & 7;
    const int rbi = blockIdx.x >> 3;
    const int hb = rbi * 16;                 // hidden slice [hb, hb+16)
    const int bb = chain * 4;                // batch slice [bb, bb+4)

    const int rgrp = tid >> 4;               // 0..31 -> rows rgrp*2, rgrp*2+1
    const int ks = tid & 15;                 // 0..15 -> k in [ks*32, ks*32+32)
    const int ks7 = ks & 7;

    // ---- load W_hh slice into registers (once): 2 rows x 32 k = 64 VGPRs ----
    float w[2][32];
#pragma unroll
    for (int i = 0; i < 2; ++i) {
        const int r = rgrp * 2 + i;                       // 0..63 = gate g=r>>4, hl=r&15
        const int j = ((r >> 4) << 9) + hb + (r & 15);
#pragma unroll
        for (int q8 = 0; q8 < 8; ++q8) {
            const float4 v = *(const float4*)(Whh + (size_t)j * 512 + ks * 32 + q8 * 4);
            w[i][q8 * 4 + 0] = v.x; w[i][q8 * 4 + 1] = v.y;
            w[i][q8 * 4 + 2] = v.z; w[i][q8 * 4 + 3] = v.w;
        }
    }
    // xwv-lane decode (ks<8): lane adds xW for (row i_x = ks>>2, batch b_x = ks&3)
    const int i_x = ks >> 2, b_x = ks & 3;
    const int r_x = rgrp * 2 + i_x;
    const int j_x = ((r_x >> 4) << 9) + hb + (r_x & 15);
    // consumer staging decode: batch b_s, h-quad q (4 h-values = 4 ring pairs)
    const int b_s = tid >> 7, q = tid & 127;
    const float* rq_base = ring + ((size_t)(bb + b_s) * 512 + (q << 2)) * 2;
    // update decode (tid<64)
    const int b_u = tid >> 4, hl_u = tid & 15;
    float c_reg = 0.0f;
    if (tid < 64) c_reg = cst[(size_t)(bb + b_u) * 512 + hb + hl_u];

    __syncthreads();

    for (int t = t0; t < t0 + TC; ++t) {
        // prefetch precomputed input-projection (plain cached load, no dependency)
        float xwv = 0.0f;
        if (ks < 8)
            xwv = xW[((size_t)(t - t0) * 2048 + j_x) * 32 + bb + b_x];

        if (t > 0) {
            // poll-stage h(t-1): tags arrive WITH the data (single round trip)
            const float* pA = rq_base + (size_t)((t - 1) & 3) * (32 * 512 * 2);
            const u32 tt = (u32)t;
            float4 A, Bv;
            do {
                A  = ldg_cv4(pA);
                Bv = ldg_cv4(pA + 4);
            } while (__float_as_uint(A.y) != tt || __float_as_uint(A.w) != tt ||
                     __float_as_uint(Bv.y) != tt || __float_as_uint(Bv.w) != tt);
            const float4 hq = {A.x, A.z, Bv.x, Bv.z};
            const int swq = q ^ ((q >> 3) & 7);          // bijective, conflict-free
            *(float4*)&xh[b_s][swq << 2] = hq;
        }
        __syncthreads();

        float acc[2][4] = {};
        if (t > 0) {
#pragma unroll
            for (int jj = 0; jj < 8; ++jj) {
                const int sq = ((ks << 3) + (jj ^ ks7)) << 2;   // swizzled quad offset
                const float4 x0 = *(const float4*)&xh[0][sq];
                const float4 x1 = *(const float4*)&xh[1][sq];
                const float4 x2 = *(const float4*)&xh[2][sq];
                const float4 x3 = *(const float4*)&xh[3][sq];
#pragma unroll
                for (int i = 0; i < 2; ++i) {
                    acc[i][0] = fmaf(w[i][jj*4+0], x0.x, acc[i][0]);
                    acc[i][0] = fmaf(w[i][jj*4+1], x0.y, acc[i][0]);
                    acc[i][0] = fmaf(w[i][jj*4+2], x0.z, acc[i][0]);
                    acc[i][0] = fmaf(w[i][jj*4+3], x0.w, acc[i][0]);
                    acc[i][1] = fmaf(w[i][jj*4+0], x1.x, acc[i][1]);
                    acc[i][1] = fmaf(w[i][jj*4+1], x1.y, acc[i][1]);
                    acc[i][1] = fmaf(w[i][jj*4+2], x1.z, acc[i][1]);
                    acc[i][1] = fmaf(w[i][jj*4+3], x1.w, acc[i][1]);
                    acc[i][2] = fmaf(w[i][jj*4+0], x2.x, acc[i][2]);
                    acc[i][2] = fmaf(w[i][jj*4+1], x2.y, acc[i][2]);
                    acc[i][2] = fmaf(w[i][jj*4+2], x2.z, acc[i][2]);
                    acc[i][2] = fmaf(w[i][jj*4+3], x2.w, acc[i][2]);
                    acc[i][3] = fmaf(w[i][jj*4+0], x3.x, acc[i][3]);
                    acc[i][3] = fmaf(w[i][jj*4+1], x3.y, acc[i][3]);
                    acc[i][3] = fmaf(w[i][jj*4+2], x3.z, acc[i][3]);
                    acc[i][3] = fmaf(w[i][jj*4+3], x3.w, acc[i][3]);
                }
            }
        }
        // fold xW in (each of the 8 outputs added by exactly one of lanes ks<8)
        if (ks < 8) acc[i_x][b_x] += xwv;
        // butterfly reduce over the 16 k-slice lanes (4 stages x 8 accs)
#pragma unroll
        for (int m = 1; m < 16; m <<= 1) {
#pragma unroll
            for (int i = 0; i < 2; ++i) {
#pragma unroll
                for (int b = 0; b < 4; ++b)
                    acc[i][b] += __shfl_xor(acc[i][b], m);
            }
        }
        if (ks == 0) {
#pragma unroll
            for (int i = 0; i < 2; ++i) {
                const int r = rgrp * 2 + i;
#pragma unroll
                for (int b = 0; b < 4; ++b)
                    gl[r & 15][b][r >> 4] = acc[i][b];
            }
        }
        __syncthreads();
        if (tid < 64) {  // one thread per (batch, hidden) pair
            const float4 gv = *(const float4*)&gl[hl_u][b_u][0];
            const float i_ = sigmoidf_(gv.x);
            const float f_ = sigmoidf_(gv.y);
            const float g_ = tanhf_(gv.z);
            const float o_ = sigmoidf_(gv.w);
            c_reg = f_ * c_reg + i_ * g_;
            const float hv = o_ * tanhf_(c_reg);
            // plain store for cross-layer GEMM / final output (kernel-boundary coherence)
            hbuf[(size_t)t * sT + (size_t)(bb + b_u) * sB + hb + hl_u] = hv;
            // tagged publication: data and tag land together, no fence, no flag
            float2 pr; pr.x = hv; pr.y = __uint_as_float((u32)(t + 1));
            stg_cv2(ring + ((size_t)(t & 3) * (32 * 512) +
                            (size_t)(bb + b_u) * 512 + hb + hl_u) * 2, pr);
        }
        __syncthreads();
    }
    if (tid < 64) cst[(size_t)(bb + b_u) * 512 + hb + hl_u] = c_reg;
}

// ============================================================================
extern "C" void kernel_launch(void* const* d_in, const int* in_sizes, int n_in,
                              void* d_out, int out_size, void* d_ws, size_t ws_size,
                              hipStream_t stream) {
    const float* inp  = (const float*)d_in[0];
    const float* Wih0 = (const float*)d_in[1];
    const float* Whh0 = (const float*)d_in[2];
    const float* bih0 = (const float*)d_in[3];
    const float* bhh0 = (const float*)d_in[4];
    const float* Wih1 = (const float*)d_in[5];
    const float* Whh1 = (const float*)d_in[6];
    const float* bih1 = (const float*)d_in[7];
    const float* bhh1 = (const float*)d_in[8];
    float* out = (float*)d_out;

    char* ws = (char*)d_ws;
    float* h0seq = (float*)ws;                              // [512][32][512]  32 MB
    float* xW    = (float*)(ws + 33554432);                 // [64][2048][32]  16 MB
    float* cst   = (float*)(ws + 50331648);                 // [2][32][512]   128 KB
    float* ring0 = (float*)(ws + 50331648 + 131072);        // [4][32][512]x2 512 KB
    float* ring1 = (float*)(ws + 50331648 + 131072 + 524288);
    // zero c-state + both rings every launch (tag epoch reset -> replay-safe)
    (void)hipMemsetAsync(ws + 50331648, 0, 131072 + 2 * 524288, stream);

    const dim3 gg(16, 16), gb(256);
    const dim3 rg(256), rb(512);

    // layer 0: x-projection GEMM + recurrence, chunked over T
    for (int c = 0; c < NCHUNK; ++c) {
        const int t0 = c * TC;
        hipLaunchKernelGGL(proj_gemm, gg, gb, 0, stream,
                           Wih0, bih0, bhh0, inp, (size_t)512 * 512, (size_t)512, t0, xW);
        hipLaunchKernelGGL(lstm_rec, rg, rb, 0, stream,
                           Whh0, xW, h0seq, (size_t)32 * 512, (size_t)512,
                           cst, ring0, t0);
    }
    // layer 1: input = h0seq; h published directly into d_out ([B][T][H])
    for (int c = 0; c < NCHUNK; ++c) {
        const int t0 = c * TC;
        hipLaunchKernelGGL(proj_gemm, gg, gb, 0, stream,
                           Wih1, bih1, bhh1, h0seq, (size_t)512, (size_t)32 * 512, t0, xW);
        hipLaunchKernelGGL(lstm_rec, rg, rb, 0, stream,
                           Whh1, xW, out, (size_t)512, (size_t)512 * 512,
                           cst + 32 * 512, ring1, t0);
    }
}